// Round 2
// baseline (424.543 us; speedup 1.0000x reference)
//
#include <hip/hip_runtime.h>

#define B_ 4096
#define T_ 32
#define A_ 4
#define OBS_ 115
#define H_ 64
#define IN_DIM_ 99
#define ACT_ 19
#define NBT (B_*T_)

typedef _Float16 f16;
typedef _Float16 f16x8 __attribute__((ext_vector_type(8)));
typedef float f32x4 __attribute__((ext_vector_type(4)));

static __device__ __forceinline__ float sigmoid_f(float x) {
    return 1.f / (1.f + __expf(-x));
}
static __device__ __forceinline__ float tanh_f(float x) {
    return 1.f - 2.f / (1.f + __expf(2.f * x));
}
static __device__ __forceinline__ f32x4 mfma16(f16x8 a, f16x8 b, f32x4 c) {
    return __builtin_amdgcn_mfma_f32_16x16x32_f16(a, b, c, 0, 0, 0);
}

// ---------------- K0: transpose proj_W (64x99) -> WT (99x64) -----------------
__global__ __launch_bounds__(256) void k0_transpose(const float* __restrict__ W,
                                                    float* __restrict__ WT) {
    int idx = blockIdx.x * 256 + threadIdx.x;
    if (idx < IN_DIM_ * H_) {
        int i = idx >> 6, h = idx & 63;
        WT[idx] = W[h * IN_DIM_ + i];
    }
}

// ------- K1: fused feature extraction + projection + LayerNorm + ReLU --------
// Block = 256 bt (8 batch rows). Phase A: thread-per-bt features -> LDS.
// Phase B: wave per 2 batch rows, lane = hidden channel; LN via shuffles.
__global__ __launch_bounds__(256) void k1_fused(const float* __restrict__ obs,
                                                const int* __restrict__ act,
                                                const float* __restrict__ WT,
                                                const float* __restrict__ pb,
                                                const float* __restrict__ lng,
                                                const float* __restrict__ lnb,
                                                f16* __restrict__ xout) {
    __shared__ float fl[256 * 25];
    __shared__ int al[256 * 5];
    int tid = threadIdx.x;
    int n = blockIdx.x * 256 + tid;                  // bt index
    const float* o = obs + (size_t)n * (A_ * OBS_);

    float px[A_], py[A_];
#pragma unroll
    for (int a = 0; a < A_; a++) { px[a] = o[a * OBS_]; py[a] = o[a * OBS_ + 1]; }
    float bx = o[88], by = o[89];
    int t0 = n & (T_ - 1);
    float pbx = bx, pby = by;
    if (t0 > 0) { pbx = o[88 - A_ * OBS_]; pby = o[89 - A_ * OBS_]; }

    float cx = (px[0] + px[1] + px[2] + px[3]) * 0.25f;
    float cy = (py[0] + py[1] + py[2] + py[3]) * 0.25f;
    float sp = 0.f;
#pragma unroll
    for (int a = 0; a < A_; a++) { float dx = px[a] - cx, dy = py[a] - cy; sp += dx * dx + dy * dy; }
    sp = sqrtf(sp * 0.25f + 1e-6f);

    float crx[A_], cry[A_];
#pragma unroll
    for (int i = 0; i < A_; i++) {
        float best = 3.4e38f; int bj = 0;
#pragma unroll
        for (int j = 0; j < A_; j++) {
            if (j == i) continue;
            float dx = px[i] - px[j], dy = py[i] - py[j];
            float d2 = dx * dx + dy * dy;
            if (d2 < best) { best = d2; bj = j; }
        }
        crx[i] = px[bj] - px[i]; cry[i] = py[bj] - py[i];
    }

    float* f = &fl[tid * 25];
    f[0] = bx; f[1] = by; f[2] = bx - pbx; f[3] = by - pby;
#pragma unroll
    for (int a = 0; a < A_; a++) { f[4 + 2 * a] = px[a]; f[5 + 2 * a] = py[a]; }
    f[12] = cx; f[13] = cy; f[14] = sp;
#pragma unroll
    for (int a = 0; a < A_; a++) { f[15 + 2 * a] = crx[a]; f[16 + 2 * a] = cry[a]; }
#pragma unroll
    for (int a = 0; a < A_; a++) al[tid * 5 + a] = act[n * A_ + a];
    __syncthreads();

    // ---- Phase B ----
    int lane = tid & 63;
    int wv = __builtin_amdgcn_readfirstlane(tid >> 6);
    float wc[23];
#pragma unroll
    for (int i = 0; i < 23; i++) wc[i] = WT[i * 64 + lane];
    float pbv = pb[lane], g = lng[lane], bb = lnb[lane];
    int b0 = blockIdx.x * 8 + wv * 2;

    for (int it = 0; it < 64; it++) {
        int lb = wv * 64 + it;
        int b = b0 + (it >> 5);
        int t = it & 31;
        const float* fp = &fl[lb * 25];
        float v = pbv;
#pragma unroll
        for (int i = 0; i < 23; i++) v += fp[i] * wc[i];
#pragma unroll
        for (int a = 0; a < A_; a++) {
            int ai = al[lb * 5 + a];
            v += WT[(23 + a * ACT_ + ai) * 64 + lane];
        }
        float s = v, ss = v * v;
#pragma unroll
        for (int m = 1; m < 64; m <<= 1) {
            s += __shfl_xor(s, m, 64);
            ss += __shfl_xor(ss, m, 64);
        }
        float mean = s * (1.f / 64.f);
        float var = ss * (1.f / 64.f) - mean * mean;
        float xn = (v - mean) * rsqrtf(var + 1e-5f) * g + bb;
        xn = fmaxf(xn, 0.f);
        xout[((size_t)t * B_ + b) * 64 + lane] = (f16)xn;
    }
}

// ------------- K2: fused 2-layer GRU (fp16 MFMA) + classifier ----------------
// 8 batch rows per block (MFMA M=16, upper 8 rows are don't-care), grid 512
// -> 2 blocks/CU so barrier stalls overlap across blocks.
#define ROWS_ 8
__global__ __launch_bounds__(256, 2) void k2_gru(
        const f16* __restrict__ x,
        const float* __restrict__ Wih0, const float* __restrict__ Whh0,
        const float* __restrict__ bih0, const float* __restrict__ bhh0,
        const float* __restrict__ Wih1, const float* __restrict__ Whh1,
        const float* __restrict__ bih1, const float* __restrict__ bhh1,
        const float* __restrict__ W1, const float* __restrict__ b1,
        const float* __restrict__ W2, const float* __restrict__ b2,
        float* __restrict__ out) {
    __shared__ __align__(16) f16 hbuf[2][2][16 * 72];   // [layer][pingpong][row*72+col]
    int tid = threadIdx.x;
    int lane = tid & 63;
    int wv = __builtin_amdgcn_readfirstlane(tid >> 6);
    int c = lane & 15, q = lane >> 4;
    int S = wv * 16;
    int rowbase = blockIdx.x * ROWS_;

    for (int k = tid; k < 2 * 2 * 16 * 72; k += 256) ((f16*)hbuf)[k] = (f16)0.f;

    auto ldw = [&](const float* W, int row0, int kcol) -> f16x8 {
        const float* p = W + (size_t)(row0 + c) * 64 + kcol + q * 8;
        f32x4 w0 = *(const f32x4*)p;
        f32x4 w1 = *(const f32x4*)(p + 4);
        f16x8 r;
        r[0] = (f16)w0[0]; r[1] = (f16)w0[1]; r[2] = (f16)w0[2]; r[3] = (f16)w0[3];
        r[4] = (f16)w1[0]; r[5] = (f16)w1[1]; r[6] = (f16)w1[2]; r[7] = (f16)w1[3];
        return r;
    };

    f16x8 wih0[3][2], whh0[3][2], wih1[3][2], whh1[3][2];
#pragma unroll
    for (int g = 0; g < 3; g++)
#pragma unroll
        for (int kf = 0; kf < 2; kf++) {
            wih0[g][kf] = ldw(Wih0, g * 64 + S, kf * 32);
            whh0[g][kf] = ldw(Whh0, g * 64 + S, kf * 32);
            wih1[g][kf] = ldw(Wih1, g * 64 + S, kf * 32);
            whh1[g][kf] = ldw(Whh1, g * 64 + S, kf * 32);
        }

    float br0 = bih0[S + c] + bhh0[S + c];
    float bz0 = bih0[64 + S + c] + bhh0[64 + S + c];
    float bi0 = bih0[128 + S + c];
    float bh0 = bhh0[128 + S + c];
    float br1 = bih1[S + c] + bhh1[S + c];
    float bz1 = bih1[64 + S + c] + bhh1[64 + S + c];
    float bi1 = bih1[128 + S + c];
    float bh1 = bhh1[128 + S + c];
    f32x4 vbr0 = {br0, br0, br0, br0}, vbz0 = {bz0, bz0, bz0, bz0};
    f32x4 vbi0 = {bi0, bi0, bi0, bi0}, vbh0 = {bh0, bh0, bh0, bh0};
    f32x4 vbr1 = {br1, br1, br1, br1}, vbz1 = {bz1, bz1, bz1, bz1};
    f32x4 vbi1 = {bi1, bi1, bi1, bi1}, vbh1 = {bh1, bh1, bh1, bh1};

    f32x4 h0c = {0.f, 0.f, 0.f, 0.f}, h1c = {0.f, 0.f, 0.f, 0.f};

    auto ldx = [&](int t, int kf) -> f16x8 {
        int row = rowbase + c;
        if (row >= B_) row = B_ - 1;                 // last block: clamp don't-care rows
        return *(const f16x8*)(x + ((size_t)t * B_ + row) * 64 + kf * 32 + q * 8);
    };

    __syncthreads();

    int p = 0;
    f16x8 xa0 = ldx(0, 0), xa1 = ldx(0, 1);
    f16x8 xn0 = xa0, xn1 = xa1;

    for (int i = 0; i <= T_; i++) {
        if (i + 1 < T_) { xn0 = ldx(i + 1, 0); xn1 = ldx(i + 1, 1); }

        f16x8 a00 = *(const f16x8*)&hbuf[0][p][c * 72 + q * 8];
        f16x8 a01 = *(const f16x8*)&hbuf[0][p][c * 72 + 32 + q * 8];

        if (i < T_) {   // layer 0
            f32x4 r = vbr0, z = vbz0, in = vbi0, hn = vbh0;
            r = mfma16(a00, whh0[0][0], r); r = mfma16(a01, whh0[0][1], r);
            r = mfma16(xa0, wih0[0][0], r); r = mfma16(xa1, wih0[0][1], r);
            z = mfma16(a00, whh0[1][0], z); z = mfma16(a01, whh0[1][1], z);
            z = mfma16(xa0, wih0[1][0], z); z = mfma16(xa1, wih0[1][1], z);
            in = mfma16(xa0, wih0[2][0], in); in = mfma16(xa1, wih0[2][1], in);
            hn = mfma16(a00, whh0[2][0], hn); hn = mfma16(a01, whh0[2][1], hn);
#pragma unroll
            for (int rr = 0; rr < 4; rr++) {
                float rg = sigmoid_f(r[rr]);
                float zg = sigmoid_f(z[rr]);
                float ng = tanh_f(in[rr] + rg * hn[rr]);
                h0c[rr] = ng + zg * (h0c[rr] - ng);
            }
        }
        if (i > 0) {    // layer 1 consumes ys0[i-1]
            f16x8 a10 = *(const f16x8*)&hbuf[1][p][c * 72 + q * 8];
            f16x8 a11 = *(const f16x8*)&hbuf[1][p][c * 72 + 32 + q * 8];
            f32x4 r = vbr1, z = vbz1, in = vbi1, hn = vbh1;
            r = mfma16(a10, whh1[0][0], r); r = mfma16(a11, whh1[0][1], r);
            r = mfma16(a00, wih1[0][0], r); r = mfma16(a01, wih1[0][1], r);
            z = mfma16(a10, whh1[1][0], z); z = mfma16(a11, whh1[1][1], z);
            z = mfma16(a00, wih1[1][0], z); z = mfma16(a01, wih1[1][1], z);
            in = mfma16(a00, wih1[2][0], in); in = mfma16(a01, wih1[2][1], in);
            hn = mfma16(a10, whh1[2][0], hn); hn = mfma16(a11, whh1[2][1], hn);
#pragma unroll
            for (int rr = 0; rr < 4; rr++) {
                float rg = sigmoid_f(r[rr]);
                float zg = sigmoid_f(z[rr]);
                float ng = tanh_f(in[rr] + rg * hn[rr]);
                h1c[rr] = ng + zg * (h1c[rr] - ng);
            }
        }
#pragma unroll
        for (int rr = 0; rr < 4; rr++) {
            hbuf[0][p ^ 1][(q * 4 + rr) * 72 + S + c] = (f16)h0c[rr];
            hbuf[1][p ^ 1][(q * 4 + rr) * 72 + S + c] = (f16)h1c[rr];
        }
        __syncthreads();
        p ^= 1;
        xa0 = xn0; xa1 = xn1;
    }

    // ---- classifier ----
    f16x8 ha0 = *(const f16x8*)&hbuf[1][p][c * 72 + q * 8];
    f16x8 ha1 = *(const f16x8*)&hbuf[1][p][c * 72 + 32 + q * 8];
    f16x8 w1f0 = ldw(W1, S, 0), w1f1 = ldw(W1, S, 32);
    float bw1 = b1[S + c];
    f32x4 hid = {bw1, bw1, bw1, bw1};
    hid = mfma16(ha0, w1f0, hid);
    hid = mfma16(ha1, w1f1, hid);
#pragma unroll
    for (int rr = 0; rr < 4; rr++) {
        float hv = fmaxf(hid[rr], 0.f);
        hbuf[0][p ^ 1][(q * 4 + rr) * 72 + S + c] = (f16)hv;
    }
    __syncthreads();
    if (wv == 0) {
        f16x8 ga0 = *(const f16x8*)&hbuf[0][p ^ 1][c * 72 + q * 8];
        f16x8 ga1 = *(const f16x8*)&hbuf[0][p ^ 1][c * 72 + 32 + q * 8];
        f16x8 w2f0 = {}, w2f1 = {};
        float bo = 0.f;
        if (c < 8) {
            w2f0 = ldw(W2, 0, 0);
            w2f1 = ldw(W2, 0, 32);
            bo = b2[c];
        }
        f32x4 lg = {bo, bo, bo, bo};
        lg = mfma16(ga0, w2f0, lg);
        lg = mfma16(ga1, w2f1, lg);
        if (c < 8) {
#pragma unroll
            for (int rr = 0; rr < 4; rr++) {
                int row = q * 4 + rr;
                if (row < ROWS_)
                    out[(size_t)(rowbase + row) * 8 + c] = lg[rr];
            }
        }
    }
}

extern "C" void kernel_launch(void* const* d_in, const int* in_sizes, int n_in,
                              void* d_out, int out_size, void* d_ws, size_t ws_size,
                              hipStream_t stream) {
    const float* obs  = (const float*)d_in[0];
    const int*   act  = (const int*)d_in[1];
    const float* projW = (const float*)d_in[2];
    const float* projb = (const float*)d_in[3];
    const float* lng  = (const float*)d_in[4];
    const float* lnb  = (const float*)d_in[5];
    const float* Wih0 = (const float*)d_in[6];
    const float* Whh0 = (const float*)d_in[7];
    const float* bih0 = (const float*)d_in[8];
    const float* bhh0 = (const float*)d_in[9];
    const float* Wih1 = (const float*)d_in[10];
    const float* Whh1 = (const float*)d_in[11];
    const float* bih1 = (const float*)d_in[12];
    const float* bhh1 = (const float*)d_in[13];
    const float* W1   = (const float*)d_in[14];
    const float* b1   = (const float*)d_in[15];
    const float* W2   = (const float*)d_in[16];
    const float* b2   = (const float*)d_in[17];
    float* out = (float*)d_out;

    char* ws = (char*)d_ws;
    float* WT = (float*)ws;                          // 25344 B
    f16*   xw = (f16*)(ws + 32768);                  // 131072*64*2 = 16 MiB

    k0_transpose<<<25, 256, 0, stream>>>(projW, WT);
    k1_fused<<<NBT / 256, 256, 0, stream>>>(obs, act, WT, projb, lng, lnb, xw);
    k2_gru<<<B_ / ROWS_, 256, 0, stream>>>(xw, Wih0, Whh0, bih0, bhh0,
                                           Wih1, Whh1, bih1, bhh1,
                                           W1, b1, W2, b2, out);
}

// Round 3
// 392.053 us; speedup vs baseline: 1.0829x; 1.0829x over previous
//
#include <hip/hip_runtime.h>

#define B_ 4096
#define T_ 32
#define A_ 4
#define OBS_ 115
#define H_ 64
#define IN_DIM_ 99
#define ACT_ 19
#define NBT (B_*T_)

typedef _Float16 f16;
typedef _Float16 f16x8 __attribute__((ext_vector_type(8)));
typedef float f32x4 __attribute__((ext_vector_type(4)));

static __device__ __forceinline__ float sigmoid_f(float x) {
    // raw v_rcp_f32: avoids IEEE div Newton-refine sequence (~4 extra VALU ops)
    return __builtin_amdgcn_rcpf(1.f + __expf(-x));
}
static __device__ __forceinline__ float tanh_f(float x) {
    // 1 - 2/(1+exp(2x)); exp->inf saturates to +1, exp->0 gives -1
    return 1.f - 2.f * __builtin_amdgcn_rcpf(1.f + __expf(2.f * x));
}
static __device__ __forceinline__ f32x4 mfma16(f16x8 a, f16x8 b, f32x4 c) {
    return __builtin_amdgcn_mfma_f32_16x16x32_f16(a, b, c, 0, 0, 0);
}

// ---------------- K0: transpose proj_W (64x99) -> WT (99x64) -----------------
__global__ __launch_bounds__(256) void k0_transpose(const float* __restrict__ W,
                                                    float* __restrict__ WT) {
    int idx = blockIdx.x * 256 + threadIdx.x;
    if (idx < IN_DIM_ * H_) {
        int i = idx >> 6, h = idx & 63;
        WT[idx] = W[h * IN_DIM_ + i];
    }
}

// ------- K1: fused feature extraction + projection + LayerNorm + ReLU --------
// Block = 256 bt (8 batch rows). Phase A: thread-per-bt features -> LDS.
// Phase B: wave per 2 batch rows, lane = hidden channel; LN via shuffles.
__global__ __launch_bounds__(256) void k1_fused(const float* __restrict__ obs,
                                                const int* __restrict__ act,
                                                const float* __restrict__ WT,
                                                const float* __restrict__ pb,
                                                const float* __restrict__ lng,
                                                const float* __restrict__ lnb,
                                                f16* __restrict__ xout) {
    __shared__ float fl[256 * 25];
    __shared__ int al[256 * 5];
    int tid = threadIdx.x;
    int n = blockIdx.x * 256 + tid;                  // bt index
    const float* o = obs + (size_t)n * (A_ * OBS_);

    float px[A_], py[A_];
#pragma unroll
    for (int a = 0; a < A_; a++) { px[a] = o[a * OBS_]; py[a] = o[a * OBS_ + 1]; }
    float bx = o[88], by = o[89];
    int t0 = n & (T_ - 1);
    float pbx = bx, pby = by;
    if (t0 > 0) { pbx = o[88 - A_ * OBS_]; pby = o[89 - A_ * OBS_]; }

    float cx = (px[0] + px[1] + px[2] + px[3]) * 0.25f;
    float cy = (py[0] + py[1] + py[2] + py[3]) * 0.25f;
    float sp = 0.f;
#pragma unroll
    for (int a = 0; a < A_; a++) { float dx = px[a] - cx, dy = py[a] - cy; sp += dx * dx + dy * dy; }
    sp = sqrtf(sp * 0.25f + 1e-6f);

    float crx[A_], cry[A_];
#pragma unroll
    for (int i = 0; i < A_; i++) {
        float best = 3.4e38f; int bj = 0;
#pragma unroll
        for (int j = 0; j < A_; j++) {
            if (j == i) continue;
            float dx = px[i] - px[j], dy = py[i] - py[j];
            float d2 = dx * dx + dy * dy;
            if (d2 < best) { best = d2; bj = j; }
        }
        crx[i] = px[bj] - px[i]; cry[i] = py[bj] - py[i];
    }

    float* f = &fl[tid * 25];
    f[0] = bx; f[1] = by; f[2] = bx - pbx; f[3] = by - pby;
#pragma unroll
    for (int a = 0; a < A_; a++) { f[4 + 2 * a] = px[a]; f[5 + 2 * a] = py[a]; }
    f[12] = cx; f[13] = cy; f[14] = sp;
#pragma unroll
    for (int a = 0; a < A_; a++) { f[15 + 2 * a] = crx[a]; f[16 + 2 * a] = cry[a]; }
#pragma unroll
    for (int a = 0; a < A_; a++) al[tid * 5 + a] = act[n * A_ + a];
    __syncthreads();

    // ---- Phase B ----
    int lane = tid & 63;
    int wv = __builtin_amdgcn_readfirstlane(tid >> 6);
    float wc[23];
#pragma unroll
    for (int i = 0; i < 23; i++) wc[i] = WT[i * 64 + lane];
    float pbv = pb[lane], g = lng[lane], bb = lnb[lane];
    int b0 = blockIdx.x * 8 + wv * 2;

    for (int it = 0; it < 64; it++) {
        int lb = wv * 64 + it;
        int b = b0 + (it >> 5);
        int t = it & 31;
        const float* fp = &fl[lb * 25];
        float v = pbv;
#pragma unroll
        for (int i = 0; i < 23; i++) v += fp[i] * wc[i];
#pragma unroll
        for (int a = 0; a < A_; a++) {
            int ai = al[lb * 5 + a];
            v += WT[(23 + a * ACT_ + ai) * 64 + lane];
        }
        float s = v, ss = v * v;
#pragma unroll
        for (int m = 1; m < 64; m <<= 1) {
            s += __shfl_xor(s, m, 64);
            ss += __shfl_xor(ss, m, 64);
        }
        float mean = s * (1.f / 64.f);
        float var = ss * (1.f / 64.f) - mean * mean;
        float xn = (v - mean) * rsqrtf(var + 1e-5f) * g + bb;
        xn = fmaxf(xn, 0.f);
        xout[((size_t)t * B_ + b) * 64 + lane] = (f16)xn;
    }
}

// ------------- K2: fused 2-layer GRU (fp16 MFMA) + classifier ----------------
// 16 batch rows per block (full MFMA tiles — no wasted gate math), grid 256.
// Iteration i: layer1 consumes ys0[i-1] (buf p) while layer0 produces ys0[i]
// (into buf p^1) -> single barrier per iteration.
__global__ __launch_bounds__(256, 1) void k2_gru(
        const f16* __restrict__ x,
        const float* __restrict__ Wih0, const float* __restrict__ Whh0,
        const float* __restrict__ bih0, const float* __restrict__ bhh0,
        const float* __restrict__ Wih1, const float* __restrict__ Whh1,
        const float* __restrict__ bih1, const float* __restrict__ bhh1,
        const float* __restrict__ W1, const float* __restrict__ b1,
        const float* __restrict__ W2, const float* __restrict__ b2,
        float* __restrict__ out) {
    __shared__ __align__(16) f16 hbuf[2][2][16 * 72];   // [layer][pingpong][row*72+col]
    int tid = threadIdx.x;
    int lane = tid & 63;
    int wv = __builtin_amdgcn_readfirstlane(tid >> 6);
    int c = lane & 15, q = lane >> 4;
    int S = wv * 16;
    int rowbase = blockIdx.x * 16;

    for (int k = tid; k < 2 * 2 * 16 * 72; k += 256) ((f16*)hbuf)[k] = (f16)0.f;

    auto ldw = [&](const float* W, int row0, int kcol) -> f16x8 {
        const float* p = W + (size_t)(row0 + c) * 64 + kcol + q * 8;
        f32x4 w0 = *(const f32x4*)p;
        f32x4 w1 = *(const f32x4*)(p + 4);
        f16x8 r;
        r[0] = (f16)w0[0]; r[1] = (f16)w0[1]; r[2] = (f16)w0[2]; r[3] = (f16)w0[3];
        r[4] = (f16)w1[0]; r[5] = (f16)w1[1]; r[6] = (f16)w1[2]; r[7] = (f16)w1[3];
        return r;
    };

    f16x8 wih0[3][2], whh0[3][2], wih1[3][2], whh1[3][2];
#pragma unroll
    for (int g = 0; g < 3; g++)
#pragma unroll
        for (int kf = 0; kf < 2; kf++) {
            wih0[g][kf] = ldw(Wih0, g * 64 + S, kf * 32);
            whh0[g][kf] = ldw(Whh0, g * 64 + S, kf * 32);
            wih1[g][kf] = ldw(Wih1, g * 64 + S, kf * 32);
            whh1[g][kf] = ldw(Whh1, g * 64 + S, kf * 32);
        }

    float br0 = bih0[S + c] + bhh0[S + c];
    float bz0 = bih0[64 + S + c] + bhh0[64 + S + c];
    float bi0 = bih0[128 + S + c];
    float bh0 = bhh0[128 + S + c];
    float br1 = bih1[S + c] + bhh1[S + c];
    float bz1 = bih1[64 + S + c] + bhh1[64 + S + c];
    float bi1 = bih1[128 + S + c];
    float bh1 = bhh1[128 + S + c];
    f32x4 vbr0 = {br0, br0, br0, br0}, vbz0 = {bz0, bz0, bz0, bz0};
    f32x4 vbi0 = {bi0, bi0, bi0, bi0}, vbh0 = {bh0, bh0, bh0, bh0};
    f32x4 vbr1 = {br1, br1, br1, br1}, vbz1 = {bz1, bz1, bz1, bz1};
    f32x4 vbi1 = {bi1, bi1, bi1, bi1}, vbh1 = {bh1, bh1, bh1, bh1};

    f32x4 h0c = {0.f, 0.f, 0.f, 0.f}, h1c = {0.f, 0.f, 0.f, 0.f};

    auto ldx = [&](int t, int kf) -> f16x8 {
        return *(const f16x8*)(x + ((size_t)t * B_ + rowbase + c) * 64 + kf * 32 + q * 8);
    };

    __syncthreads();   // LDS zeros visible

    int p = 0;
    f16x8 xa0 = ldx(0, 0), xa1 = ldx(0, 1);
    f16x8 xn0 = xa0, xn1 = xa1;

    for (int i = 0; i <= T_; i++) {
        if (i + 1 < T_) { xn0 = ldx(i + 1, 0); xn1 = ldx(i + 1, 1); }

        f16x8 a00 = *(const f16x8*)&hbuf[0][p][c * 72 + q * 8];
        f16x8 a01 = *(const f16x8*)&hbuf[0][p][c * 72 + 32 + q * 8];

        if (i < T_) {   // layer 0: h0 <- f(h0, x_i)
            f32x4 r = vbr0, z = vbz0, in = vbi0, hn = vbh0;
            r = mfma16(a00, whh0[0][0], r); r = mfma16(a01, whh0[0][1], r);
            r = mfma16(xa0, wih0[0][0], r); r = mfma16(xa1, wih0[0][1], r);
            z = mfma16(a00, whh0[1][0], z); z = mfma16(a01, whh0[1][1], z);
            z = mfma16(xa0, wih0[1][0], z); z = mfma16(xa1, wih0[1][1], z);
            in = mfma16(xa0, wih0[2][0], in); in = mfma16(xa1, wih0[2][1], in);
            hn = mfma16(a00, whh0[2][0], hn); hn = mfma16(a01, whh0[2][1], hn);
#pragma unroll
            for (int rr = 0; rr < 4; rr++) {
                float rg = sigmoid_f(r[rr]);
                float zg = sigmoid_f(z[rr]);
                float ng = tanh_f(in[rr] + rg * hn[rr]);
                h0c[rr] = ng + zg * (h0c[rr] - ng);
            }
        }
        if (i > 0) {    // layer 1: h1 <- g(h1, ys0[i-1]=a00/a01)
            f16x8 a10 = *(const f16x8*)&hbuf[1][p][c * 72 + q * 8];
            f16x8 a11 = *(const f16x8*)&hbuf[1][p][c * 72 + 32 + q * 8];
            f32x4 r = vbr1, z = vbz1, in = vbi1, hn = vbh1;
            r = mfma16(a10, whh1[0][0], r); r = mfma16(a11, whh1[0][1], r);
            r = mfma16(a00, wih1[0][0], r); r = mfma16(a01, wih1[0][1], r);
            z = mfma16(a10, whh1[1][0], z); z = mfma16(a11, whh1[1][1], z);
            z = mfma16(a00, wih1[1][0], z); z = mfma16(a01, wih1[1][1], z);
            in = mfma16(a00, wih1[2][0], in); in = mfma16(a01, wih1[2][1], in);
            hn = mfma16(a10, whh1[2][0], hn); hn = mfma16(a11, whh1[2][1], hn);
#pragma unroll
            for (int rr = 0; rr < 4; rr++) {
                float rg = sigmoid_f(r[rr]);
                float zg = sigmoid_f(z[rr]);
                float ng = tanh_f(in[rr] + rg * hn[rr]);
                h1c[rr] = ng + zg * (h1c[rr] - ng);
            }
        }
#pragma unroll
        for (int rr = 0; rr < 4; rr++) {
            hbuf[0][p ^ 1][(q * 4 + rr) * 72 + S + c] = (f16)h0c[rr];
            hbuf[1][p ^ 1][(q * 4 + rr) * 72 + S + c] = (f16)h1c[rr];
        }
        __syncthreads();
        p ^= 1;
        xa0 = xn0; xa1 = xn1;
    }

    // ---- classifier ----
    f16x8 ha0 = *(const f16x8*)&hbuf[1][p][c * 72 + q * 8];
    f16x8 ha1 = *(const f16x8*)&hbuf[1][p][c * 72 + 32 + q * 8];
    f16x8 w1f0 = ldw(W1, S, 0), w1f1 = ldw(W1, S, 32);
    float bw1 = b1[S + c];
    f32x4 hid = {bw1, bw1, bw1, bw1};
    hid = mfma16(ha0, w1f0, hid);
    hid = mfma16(ha1, w1f1, hid);
#pragma unroll
    for (int rr = 0; rr < 4; rr++) {
        float hv = fmaxf(hid[rr], 0.f);
        hbuf[0][p ^ 1][(q * 4 + rr) * 72 + S + c] = (f16)hv;
    }
    __syncthreads();
    if (wv == 0) {
        f16x8 ga0 = *(const f16x8*)&hbuf[0][p ^ 1][c * 72 + q * 8];
        f16x8 ga1 = *(const f16x8*)&hbuf[0][p ^ 1][c * 72 + 32 + q * 8];
        f16x8 w2f0 = {}, w2f1 = {};
        float bo = 0.f;
        if (c < 8) {
            w2f0 = ldw(W2, 0, 0);
            w2f1 = ldw(W2, 0, 32);
            bo = b2[c];
        }
        f32x4 lg = {bo, bo, bo, bo};
        lg = mfma16(ga0, w2f0, lg);
        lg = mfma16(ga1, w2f1, lg);
        if (c < 8) {
#pragma unroll
            for (int rr = 0; rr < 4; rr++)
                out[(size_t)(rowbase + q * 4 + rr) * 8 + c] = lg[rr];
        }
    }
}

extern "C" void kernel_launch(void* const* d_in, const int* in_sizes, int n_in,
                              void* d_out, int out_size, void* d_ws, size_t ws_size,
                              hipStream_t stream) {
    const float* obs  = (const float*)d_in[0];
    const int*   act  = (const int*)d_in[1];
    const float* projW = (const float*)d_in[2];
    const float* projb = (const float*)d_in[3];
    const float* lng  = (const float*)d_in[4];
    const float* lnb  = (const float*)d_in[5];
    const float* Wih0 = (const float*)d_in[6];
    const float* Whh0 = (const float*)d_in[7];
    const float* bih0 = (const float*)d_in[8];
    const float* bhh0 = (const float*)d_in[9];
    const float* Wih1 = (const float*)d_in[10];
    const float* Whh1 = (const float*)d_in[11];
    const float* bih1 = (const float*)d_in[12];
    const float* bhh1 = (const float*)d_in[13];
    const float* W1   = (const float*)d_in[14];
    const float* b1   = (const float*)d_in[15];
    const float* W2   = (const float*)d_in[16];
    const float* b2   = (const float*)d_in[17];
    float* out = (float*)d_out;

    char* ws = (char*)d_ws;
    float* WT = (float*)ws;                          // 25344 B
    f16*   xw = (f16*)(ws + 32768);                  // 131072*64*2 = 16 MiB

    k0_transpose<<<25, 256, 0, stream>>>(projW, WT);
    k1_fused<<<NBT / 256, 256, 0, stream>>>(obs, act, WT, projb, lng, lnb, xw);
    k2_gru<<<B_ / 16, 256, 0, stream>>>(xw, Wih0, Whh0, bih0, bhh0,
                                        Wih1, Whh1, bih1, bhh1,
                                        W1, b1, W2, b2, out);
}